// Round 12
// baseline (416.524 us; speedup 1.0000x reference)
//
#include <hip/hip_runtime.h>
#include <hip/hip_bf16.h>
#include <math.h>

#define SELU_SCALE 1.0507009873554805f
#define SELU_SA    1.7580993408473766f   // scale*alpha

typedef __attribute__((ext_vector_type(8))) short short8;
typedef __attribute__((ext_vector_type(4))) short short4v;
typedef __attribute__((ext_vector_type(4))) float f32x4;

__device__ __forceinline__ float selu_f(float x){
    return x > 0.f ? SELU_SCALE * x : fmaf(SELU_SA, __expf(x), -SELU_SA);
}

__device__ __forceinline__ unsigned short bfc(float v){
    __hip_bfloat16 h = __float2bfloat16(v);
    return __builtin_bit_cast(unsigned short, h);
}
__device__ __forceinline__ float f_bf(unsigned short u){
    unsigned int x = ((unsigned int)u) << 16;
    return __builtin_bit_cast(float, x);
}

__device__ __forceinline__ float warp_max(float v){
    #pragma unroll
    for(int o=32;o>0;o>>=1) v = fmaxf(v,__shfl_down(v,o,64));
    return v;
}

// ---------------- unified weight prep
__global__ void k_prep(const float* __restrict__ f1w, const float* __restrict__ wq,
                       const float* __restrict__ wk, const float* __restrict__ wv,
                       const float* __restrict__ w1, const float* __restrict__ w2,
                       const float* __restrict__ w3,
                       float* __restrict__ wt, float* __restrict__ wqt,
                       float* __restrict__ wkt, float* __restrict__ wvt,
                       short* __restrict__ w1bf, short* __restrict__ w2bf,
                       short* __restrict__ w3bf){
    int idx = blockIdx.x*256 + threadIdx.x;
    if(idx < 131072){ int r = idx >> 10, cc = idx & 1023; wt[cc*128 + r] = f1w[idx]; return; }
    idx -= 131072;
    if(idx < 16384){ int r = idx >> 7, cc = idx & 127; wqt[cc*128 + r] = wq[idx]; return; }
    idx -= 16384;
    if(idx < 16384){ int r = idx >> 7, cc = idx & 127; wkt[cc*128 + r] = wk[idx]; return; }
    idx -= 16384;
    if(idx < 16384){ int r = idx >> 7, cc = idx & 127; wvt[cc*128 + r] = wv[idx]; return; }
    idx -= 16384;
    if(idx < 49152){
        int t = idx >> 11, rem = idx & 2047;
        int oc = rem >> 5, ic = rem & 31;
        w2bf[idx] = (short)bfc(w2[oc*768 + ic*24 + t]);
        return;
    }
    idx -= 49152;
    if(idx < 196608){
        int t = idx >> 13, rem = idx & 8191;
        int oc = rem >> 6, ic = rem & 63;
        w3bf[idx] = (short)bfc(w3[oc*1536 + ic*24 + t]);
        return;
    }
    idx -= 196608;
    if(idx < 1024){
        int oc = idx >> 5, k = idx & 31;
        w1bf[idx] = (k < 24) ? (short)bfc(w1[oc*24 + k]) : (short)0;
    }
}

// ============ Stage 1 (MFMA): conv1(1->32) + SELU + GN(1ch/grp) + maxpool(2,4)
__global__ __launch_bounds__(1024,1) void k_conv1m(
    const float* __restrict__ x, const short* __restrict__ w1bf,
    const float* __restrict__ bias, const float* __restrict__ g,
    const float* __restrict__ be, unsigned short* __restrict__ out)
{
    int s = blockIdx.x, tid = threadIdx.x;
    int l = tid & 63, wv = tid >> 6;          // wv 0..15
    int c = l & 15, qr = l >> 4;
    __shared__ char smem[128752];
    short* sdup = (short*)smem;               // 79 rows x 528 B = 41,712
    char* pmaxb = smem + 41712;               // [576 win x 72 B] = 41,472
    char* pminb = smem + 83184;               // 41,472
    float* sredf = (float*)(smem + 124656);   // [16][4][8][2] = 1024 floats
    __shared__ float scsh[64];                // [32 oc][sc,sh]

    const float* xs = x + (size_t)s*4608;
    for(int i = tid; i < 5056; i += 1024){
        int yp = i >> 6, xx = i & 63;
        unsigned long long pk = 0ull;
        if(yp >= 2 && yp < 74){
            const float* row = xs + (yp-2)*64;
            #pragma unroll
            for(int t=0;t<4;t++){
                int cp = xx + t;
                float f = (cp>=1 && cp<65) ? row[cp-1] : 0.f;
                pk |= (unsigned long long)bfc(f) << (16*t);
            }
        }
        *(unsigned long long*)((char*)sdup + yp*528 + (xx&3)*128 + (xx>>2)*8) = pk;
    }
    short8 a0 = *(const short8*)(w1bf + c*32 + qr*8);
    short8 a1 = *(const short8*)(w1bf + (16+c)*32 + qr*8);
    float bias8[8];
    #pragma unroll
    for(int t=0;t<2;t++)
        #pragma unroll
        for(int r=0;r<4;r++) bias8[t*4+r] = bias[t*16 + qr*4 + r];
    float ssum8[8], ssq8[8];
    #pragma unroll
    for(int i=0;i<8;i++){ ssum8[i]=0.f; ssq8[i]=0.f; }
    __syncthreads();

    int nu, py0;
    if(wv < 4){ nu = 3; py0 = wv*3; } else { nu = 2; py0 = 12 + (wv-4)*2; }
    #pragma unroll 1
    for(int u=0; u<nu; u++){
        int py = py0 + u;
        float pmx[8], pmn[8];
        #pragma unroll
        for(int i=0;i<8;i++){ pmx[i]=-INFINITY; pmn[i]=INFINITY; }
        #pragma unroll
        for(int off=0; off<4; off++){
            const char* bb = (const char*)sdup + off*128 + c*8;
            #pragma unroll
            for(int rr=0; rr<2; rr++){
                int y = py*2 + rr;
                short4v lo = *(const short4v*)(bb + (y+2*qr)*528);
                short4v hi = *(const short4v*)(bb + (y+2*qr+1)*528);
                short8 bfrag = __builtin_shufflevector(lo, hi, 0,1,2,3,4,5,6,7);
                f32x4 d0 = __builtin_amdgcn_mfma_f32_16x16x32_bf16(a0, bfrag, (f32x4){0.f,0.f,0.f,0.f}, 0,0,0);
                f32x4 d1 = __builtin_amdgcn_mfma_f32_16x16x32_bf16(a1, bfrag, (f32x4){0.f,0.f,0.f,0.f}, 0,0,0);
                #pragma unroll
                for(int r=0;r<4;r++){
                    float v0 = selu_f(d0[r] + bias8[r]);
                    float v1 = selu_f(d1[r] + bias8[4+r]);
                    ssum8[r]   += v0; ssq8[r]   = fmaf(v0,v0,ssq8[r]);
                    ssum8[4+r] += v1; ssq8[4+r] = fmaf(v1,v1,ssq8[4+r]);
                    pmx[r]   = fmaxf(pmx[r],   v0); pmn[r]   = fminf(pmn[r],   v0);
                    pmx[4+r] = fmaxf(pmx[4+r], v1); pmn[4+r] = fminf(pmn[4+r], v1);
                }
            }
        }
        int base = (py*16 + c)*72;
        #pragma unroll
        for(int t=0;t<2;t++){
            unsigned long long mpk=0ull, npk=0ull;
            #pragma unroll
            for(int r=0;r<4;r++){
                mpk |= (unsigned long long)bfc(pmx[t*4+r]) << (16*r);
                npk |= (unsigned long long)bfc(pmn[t*4+r]) << (16*r);
            }
            *(unsigned long long*)(pmaxb + base + t*32 + qr*8) = mpk;
            *(unsigned long long*)(pminb + base + t*32 + qr*8) = npk;
        }
    }
    #pragma unroll
    for(int off=1; off<16; off<<=1){
        #pragma unroll
        for(int i=0;i<8;i++){
            ssum8[i] += __shfl_xor(ssum8[i], off);
            ssq8[i]  += __shfl_xor(ssq8[i],  off);
        }
    }
    if(c == 0){
        #pragma unroll
        for(int i=0;i<8;i++){
            sredf[((wv*4 + qr)*8 + i)*2]     = ssum8[i];
            sredf[((wv*4 + qr)*8 + i)*2 + 1] = ssq8[i];
        }
    }
    __syncthreads();
    if(tid < 32){
        int oc = tid;
        int t = oc >> 4, rem = oc & 15, q = rem >> 2, r = rem & 3;
        int i = t*4 + r;
        float sum=0.f, sq=0.f;
        for(int w=0; w<16; w++){
            sum += sredf[((w*4+q)*8+i)*2];
            sq  += sredf[((w*4+q)*8+i)*2+1];
        }
        float mean = sum*(1.f/4608.f);
        float var  = sq*(1.f/4608.f) - mean*mean;
        float inv  = rsqrtf(var + 1e-5f);
        float sc = g[oc]*inv;
        scsh[oc*2]   = sc;
        scsh[oc*2+1] = be[oc] - mean*sc;
    }
    __syncthreads();
    unsigned short* ob = out + (size_t)s*18432;
    for(int i = tid; i < 18432; i += 1024){
        int oc = i / 576, wpx = i - oc*576;
        float sc = scsh[oc*2], sh = scsh[oc*2+1];
        int boff = wpx*72 + oc*2;
        float vm = f_bf(*(unsigned short*)(pmaxb + boff));
        float vn = f_bf(*(unsigned short*)(pminb + boff));
        ob[i] = bfc(fmaf(sc, (sc >= 0.f) ? vm : vn, sh));
    }
}

// ============ Fused stages 2+3 (MFMA), LDS-read-optimized.
// 768 thr = 12 waves. Phase A (conv2): wave = pool-row (3 rows), ALL 4 oc-tiles
// -> each ds_read_b128 feeds 4 MFMA. Phase B (conv3): 4 waves x 2 oc-tiles.
__global__ __launch_bounds__(768,2) void k_conv23(
    const unsigned short* __restrict__ in, const short* __restrict__ w2bf,
    const float* __restrict__ b2, const float* __restrict__ g2,
    const float* __restrict__ e2,
    const short* __restrict__ w3bf,
    const float* __restrict__ b3, const float* __restrict__ g3,
    const float* __restrict__ e3, float* __restrict__ e0)
{
    int s = blockIdx.x, tid = threadIdx.x;
    int l = tid & 63, wv = tid >> 6;          // wv 0..11
    int xc = l & 15, qr = l >> 4;
    __shared__ char cs[69888];                // sinb 52480 (later scratch) + s3in 17408
    short* sinb = (short*)cs;
    char*  s3in = cs + 52480;
    __shared__ float sredB[12][64][2];        // per-wave per-oc sum/sq (conv2 GN)
    __shared__ float scsh2[128];              // [64 oc][sc,sh]
    for(int i=tid;i<17472;i+=768) ((int*)cs)[i] = 0;
    __syncthreads();
    const unsigned short* ibase = in + (size_t)s*18432;
    for(int i=tid;i<9216;i+=768){
        int icp = i/576, px = i - icp*576;
        int ic = icp*2;
        unsigned int v0 = ibase[ic*576 + px];
        unsigned int v1 = ibase[(ic+1)*576 + px];
        int R = (px>>4)+2, C = (px&15)+1;
        int key = (C>>1)&3;
        int q0 = ic>>3;
        int byteoff = (R*20+C)*64 + (((q0^key)&3)<<4) + (ic&7)*2;
        *(unsigned int*)((char*)sinb + byteoff) = v0 | (v1<<16);
    }
    __syncthreads();
    // -------- Phase A: conv2. wave wv -> rows 3wv..3wv+2, oc-tiles 0..3.
    f32x4 acc[4][3];
    #pragma unroll
    for(int t=0;t<4;t++)
        #pragma unroll
        for(int yt=0;yt<3;yt++) acc[t][yt] = (f32x4){0.f,0.f,0.f,0.f};
    const short8* wb = (const short8*)w2bf;
    short8 a[4], na[4];
    #pragma unroll
    for(int t=0;t<4;t++) a[t] = wb[(t*16 + xc)*4 + qr];
    char* sb = (char*)sinb;
    int w3row = wv*3;
    #pragma unroll 1
    for(int tap=0; tap<24; tap++){
        if(tap<23){
            #pragma unroll
            for(int t=0;t<4;t++) na[t] = wb[((tap+1)*64 + t*16 + xc)*4 + qr];
        }
        int kh = tap>>2, kw = tap&3;
        int C = xc + kw;
        int cb = C*64 + (((qr ^ ((C>>1)&3))&3)<<4);
        #pragma unroll
        for(int yt=0;yt<3;yt++){
            short8 bf_ = *(const short8*)(sb + (w3row + yt + kh)*1280 + cb);
            acc[0][yt] = __builtin_amdgcn_mfma_f32_16x16x32_bf16(a[0], bf_, acc[0][yt], 0,0,0);
            acc[1][yt] = __builtin_amdgcn_mfma_f32_16x16x32_bf16(a[1], bf_, acc[1][yt], 0,0,0);
            acc[2][yt] = __builtin_amdgcn_mfma_f32_16x16x32_bf16(a[2], bf_, acc[2][yt], 0,0,0);
            acc[3][yt] = __builtin_amdgcn_mfma_f32_16x16x32_bf16(a[3], bf_, acc[3][yt], 0,0,0);
        }
        #pragma unroll
        for(int t=0;t<4;t++) a[t] = na[t];
    }
    // SELU + per-oc partial stats (this wave: 3 rows x 16 cols per oc)
    #pragma unroll
    for(int t=0;t<4;t++){
        #pragma unroll
        for(int r=0;r<4;r++){
            int oc = t*16 + qr*4 + r;
            float bb = b2[oc];
            float sv=0.f, qv=0.f;
            #pragma unroll
            for(int yt=0;yt<3;yt++){
                float v = selu_f(acc[t][yt][r] + bb);
                acc[t][yt][r] = v;
                sv += v; qv = fmaf(v,v,qv);
            }
            #pragma unroll
            for(int off=1;off<16;off<<=1){ sv += __shfl_xor(sv,off); qv += __shfl_xor(qv,off); }
            if(xc==0){ sredB[wv][oc][0]=sv; sredB[wv][oc][1]=qv; }
        }
    }
    __syncthreads();
    if(tid < 32){
        int gidx = tid;                      // GN group of 2 oc
        int oc0 = gidx*2;
        float sum=0.f, sq=0.f;
        for(int w=0;w<12;w++){
            sum += sredB[w][oc0][0] + sredB[w][oc0+1][0];
            sq  += sredB[w][oc0][1] + sredB[w][oc0+1][1];
        }
        float mean = sum*(1.f/1152.f);
        float var  = sq*(1.f/1152.f) - mean*mean;
        float inv  = rsqrtf(var + 1e-5f);
        #pragma unroll
        for(int o2=0;o2<2;o2++){
            int oc = oc0+o2;
            float sc = g2[oc]*inv;
            scsh2[oc*2]   = sc;
            scsh2[oc*2+1] = e2[oc] - mean*sc;
        }
    }
    __syncthreads();
    // GN apply + pool(3x4) -> s3in (wave wv owns pool row wv)
    #pragma unroll
    for(int t=0;t<4;t++){
        #pragma unroll
        for(int r=0;r<4;r++){
            int oc = t*16 + qr*4 + r;
            float sc = scsh2[oc*2], sh = scsh2[oc*2+1];
            float m = fmaxf(fmaxf(acc[t][0][r], acc[t][1][r]), acc[t][2][r]);
            m = m*sc;                        // monotone only if sc>=0; handle sign:
            // need min when sc<0: recompute via min
            float mn = fminf(fminf(acc[t][0][r], acc[t][1][r]), acc[t][2][r]);
            float vsel = (sc >= 0.f) ? m : mn*sc;
            // reduce across 4 cols (lanes xc, xor 1,2): pooled = max over cols of (v*sc+sh)
            float pv = vsel + sh;
            pv = fmaxf(pv, __shfl_xor(pv,1));
            pv = fmaxf(pv, __shfl_xor(pv,2));
            if((xc&3)==0){
                int R = wv + 2;
                int C = (xc>>2) + 1;
                int key = ((R&1)<<2) | (C&3);
                int q0 = oc>>3;
                *(unsigned short*)(s3in + (R*8+C)*128 + (((q0^key)&7)<<4) + (oc&7)*2) = bfc(pv);
            }
        }
    }
    __syncthreads();
    // -------- Phase B: conv3, 4 waves x 2 oc-tiles (oc 32wv..32wv+31)
    if(wv < 4){
        int yl = xc >> 2, xl = xc & 3;
        f32x4 acc3[2][3];
        #pragma unroll
        for(int o=0;o<2;o++)
            #pragma unroll
            for(int yt=0;yt<3;yt++) acc3[o][yt] = (f32x4){0.f,0.f,0.f,0.f};
        const short8* wb3 = (const short8*)w3bf;
        int ar0 = wv*32 + xc, ar1 = wv*32 + 16 + xc;
        short8 a30 = wb3[ar0*8 + qr];
        short8 a31 = wb3[ar1*8 + qr];
        #pragma unroll 1
        for(int t2=0; t2<48; t2++){
            short8 n30, n31;
            if(t2<47){
                int nt = t2+1;
                n30 = wb3[((nt>>1)*128 + ar0)*8 + (nt&1)*4 + qr];
                n31 = wb3[((nt>>1)*128 + ar1)*8 + (nt&1)*4 + qr];
            }
            int tap = t2>>1, ks = t2&1;
            int kh = tap>>2, kw = tap&3;
            int C = xl + kw;
            int q0 = ks*4 + qr;
            #pragma unroll
            for(int yt=0;yt<3;yt++){
                int R = yt*4 + yl + kh;
                int key = ((R&1)<<2) | (C&3);
                short8 bf_ = *(const short8*)(s3in + (R*8+C)*128 + (((q0^key)&7)<<4));
                acc3[0][yt] = __builtin_amdgcn_mfma_f32_16x16x32_bf16(a30, bf_, acc3[0][yt], 0,0,0);
                acc3[1][yt] = __builtin_amdgcn_mfma_f32_16x16x32_bf16(a31, bf_, acc3[1][yt], 0,0,0);
            }
            a30 = n30; a31 = n31;
        }
        // epilogue: bias + SELU + GN (group = qr quad) + affine -> wave scratch
        float* scr = (float*)cs + wv*1536;   // 32 oc x 48 px
        #pragma unroll
        for(int o=0;o<2;o++){
            int ocb3 = wv*32 + o*16 + qr*4;
            float c0 = b3[ocb3], c1 = b3[ocb3+1], c2 = b3[ocb3+2], c3 = b3[ocb3+3];
            float ssum=0.f, ssq=0.f;
            #pragma unroll
            for(int yt=0;yt<3;yt++){
                float v0=selu_f(acc3[o][yt][0]+c0), v1=selu_f(acc3[o][yt][1]+c1);
                float v2=selu_f(acc3[o][yt][2]+c2), v3=selu_f(acc3[o][yt][3]+c3);
                acc3[o][yt][0]=v0; acc3[o][yt][1]=v1; acc3[o][yt][2]=v2; acc3[o][yt][3]=v3;
                ssum += v0+v1+v2+v3; ssq += v0*v0+v1*v1+v2*v2+v3*v3;
            }
            #pragma unroll
            for(int off=1;off<16;off<<=1){ ssum+=__shfl_xor(ssum,off); ssq+=__shfl_xor(ssq,off); }
            float mean3 = ssum*(1.f/192.f);
            float var3  = ssq*(1.f/192.f) - mean3*mean3;
            float inv3  = rsqrtf(var3 + 1e-5f);
            #pragma unroll
            for(int r=0;r<4;r++){
                int oc = ocb3 + r;
                float sc = g3[oc]*inv3, sh = e3[oc] - mean3*sc;
                #pragma unroll
                for(int yt=0;yt<3;yt++)
                    scr[(o*16 + qr*4 + r)*48 + (yt*4+yl)*4 + xl] = acc3[o][yt][r]*sc + sh;
            }
        }
    }
    __syncthreads();
    if(wv < 4){
        // pool 3x2: lane -> oc_l = l>>1 (32 oc), x2 = l&1
        int oc_l = l >> 1, x2 = l & 1;
        const float* srd = (const float*)cs + wv*1536 + oc_l*48;
        float* eo = e0 + (size_t)s*1024 + (wv*32 + oc_l)*8;
        #pragma unroll
        for(int py=0;py<4;py++){
            float m = srd[(py*3)*4 + x2*2];
            m = fmaxf(m, srd[(py*3)*4 + x2*2+1]);
            m = fmaxf(m, srd[(py*3+1)*4 + x2*2]);
            m = fmaxf(m, srd[(py*3+1)*4 + x2*2+1]);
            m = fmaxf(m, srd[(py*3+2)*4 + x2*2]);
            m = fmaxf(m, srd[(py*3+2)*4 + x2*2+1]);
            eo[py*2 + x2] = m;
        }
    }
}

// ---------------- FC1 + SELU + l2norm + QKV + PE, batched 4 samples/block.
__global__ __launch_bounds__(512) void k_fcqkv(
    const float* __restrict__ e0, const float* __restrict__ wt,
    const float* __restrict__ bias, float* __restrict__ et,
    const float* __restrict__ wqt, const float* __restrict__ bq,
    const float* __restrict__ wkt, const float* __restrict__ bk,
    const float* __restrict__ wvt, const float* __restrict__ bv,
    float* __restrict__ q, float* __restrict__ kp, float* __restrict__ v)
{
    int s0 = blockIdx.x*4, tid = threadIdx.x;
    int j = tid & 127, q4 = tid >> 7;
    __shared__ float se[4][1024];
    __shared__ float sp[4][4][128];
    __shared__ float sredn[4][2];
    __shared__ float se2[4][128];
    __shared__ float sp3[3][4][4][128];
    for(int i=tid;i<4096;i+=512){
        int sl = i >> 10, ii = i & 1023;
        se[sl][ii] = e0[(size_t)(s0+sl)*1024 + ii];
    }
    __syncthreads();
    float acc[4] = {0.f,0.f,0.f,0.f};
    const float* wp = wt + (size_t)q4*256*128 + j;
    const int ibase = q4*256;
    #pragma unroll 4
    for(int i=0;i<256;i++){
        float w = wp[(size_t)i*128];
        #pragma unroll
        for(int sl=0;sl<4;sl++) acc[sl] = fmaf(se[sl][ibase+i], w, acc[sl]);
    }
    #pragma unroll
    for(int sl=0;sl<4;sl++) sp[sl][q4][j] = acc[sl];
    __syncthreads();
    int sl2 = q4, lane = tid & 63, wv_ = tid >> 6;
    float vfc = selu_f(bias[j] + sp[sl2][0][j] + sp[sl2][1][j] + sp[sl2][2][j] + sp[sl2][3][j]);
    float a = vfc*vfc;
    #pragma unroll
    for(int o=1;o<64;o<<=1) a += __shfl_xor(a, o);
    if(lane==0) sredn[sl2][wv_&1] = a;
    __syncthreads();
    float den = fmaxf(sqrtf(sredn[sl2][0]+sredn[sl2][1]), 1e-12f);
    float ev = vfc/den;
    se2[sl2][j] = ev;
    et[(size_t)j*1024 + s0+sl2] = ev;
    __syncthreads();
    float aq[4]={0,0,0,0}, ak[4]={0,0,0,0}, av[4]={0,0,0,0};
    int i0b = q4*32;
    #pragma unroll 4
    for(int i=0;i<32;i++){
        float wqv = wqt[(i0b+i)*128 + j];
        float wkv = wkt[(i0b+i)*128 + j];
        float wvv = wvt[(i0b+i)*128 + j];
        #pragma unroll
        for(int sl=0;sl<4;sl++){
            float f = se2[sl][i0b+i];
            aq[sl] = fmaf(f, wqv, aq[sl]);
            ak[sl] = fmaf(f, wkv, ak[sl]);
            av[sl] = fmaf(f, wvv, av[sl]);
        }
    }
    #pragma unroll
    for(int sl=0;sl<4;sl++){
        sp3[0][sl][q4][j] = aq[sl];
        sp3[1][sl][q4][j] = ak[sl];
        sp3[2][sl][q4][j] = av[sl];
    }
    __syncthreads();
    float vq = selu_f(bq[j] + sp3[0][sl2][0][j]+sp3[0][sl2][1][j]+sp3[0][sl2][2][j]+sp3[0][sl2][3][j]);
    float vk = selu_f(bk[j] + sp3[1][sl2][0][j]+sp3[1][sl2][1][j]+sp3[1][sl2][2][j]+sp3[1][sl2][3][j]);
    float vv = selu_f(bv[j] + sp3[2][sl2][0][j]+sp3[2][sl2][1][j]+sp3[2][sl2][2][j]+sp3[2][sl2][3][j]);
    int i2 = j & ~1;
    float dv = __expf(-(float)i2 * 0.07195578412155481f);
    float ang = (float)(s0+sl2) * dv;
    float pe = (j & 1) ? cosf(ang) : sinf(ang);
    q[(size_t)(s0+sl2)*128+j]  = vq;
    kp[(size_t)(s0+sl2)*128+j] = vk + pe;
    v[(size_t)(s0+sl2)*128+j]  = vv;
}

// ---------------- fused attention, batched 4 samples/block; av written transposed
__global__ __launch_bounds__(512) void k_attnav(
    const float* __restrict__ q, const float* __restrict__ kp,
    const float* __restrict__ v, float* __restrict__ avt)
{
    int s0 = blockIdx.x*4, tid = threadIdx.x;
    __shared__ float4 sq4[4][32];
    __shared__ float p[4][1024];
    __shared__ float spart[4][4][128];
    __shared__ float smx[4][2], ssm[4][2];
    ((float*)sq4)[tid] = q[(size_t)s0*128 + tid];
    __syncthreads();
    #pragma unroll
    for(int h=0;h<2;h++){
        int t = tid + h*512;
        const float4* kr = (const float4*)(kp + (size_t)t*128);
        float d[4] = {0.f,0.f,0.f,0.f};
        #pragma unroll 4
        for(int i=0;i<32;i++){
            float4 kv = kr[i];
            #pragma unroll
            for(int sl=0;sl<4;sl++){
                float4 qv = sq4[sl][i];
                d[sl] += kv.x*qv.x + kv.y*qv.y + kv.z*qv.z + kv.w*qv.w;
            }
        }
        #pragma unroll
        for(int sl=0;sl<4;sl++) p[sl][t] = d[sl]*0.08838834764831845f;
    }
    __syncthreads();
    int sl2 = tid>>7, t2 = tid&127, lane = tid&63, wv_ = tid>>6;
    float vals[8];
    float m = -INFINITY;
    #pragma unroll
    for(int k=0;k<8;k++){ vals[k] = p[sl2][t2 + k*128]; m = fmaxf(m, vals[k]); }
    #pragma unroll
    for(int o=1;o<64;o<<=1) m = fmaxf(m, __shfl_xor(m,o));
    if(lane==0) smx[sl2][wv_&1] = m;
    __syncthreads();
    m = fmaxf(smx[sl2][0], smx[sl2][1]);
    float lsum = 0.f;
    #pragma unroll
    for(int k=0;k<8;k++){ vals[k] = __expf(vals[k]-m); lsum += vals[k]; }
    #pragma unroll
    for(int o=1;o<64;o<<=1) lsum += __shfl_xor(lsum,o);
    if(lane==0) ssm[sl2][wv_&1] = lsum;
    __syncthreads();
    float invs = 1.f/(ssm[sl2][0]+ssm[sl2][1]);
    #pragma unroll
    for(int k=0;k<8;k++) p[sl2][t2+k*128] = vals[k]*invs;
    __syncthreads();
    int j = tid & 127, q4 = tid >> 7;
    float acc[4] = {0,0,0,0};
    int t0 = q4*256;
    #pragma unroll 2
    for(int t=t0;t<t0+256;t++){
        float vv = v[(size_t)t*128 + j];
        #pragma unroll
        for(int sl=0;sl<4;sl++) acc[sl] = fmaf(p[sl][t], vv, acc[sl]);
    }
    #pragma unroll
    for(int sl=0;sl<4;sl++) spart[sl][q4][j] = acc[sl];
    __syncthreads();
    avt[(size_t)j*1024 + s0+sl2] = spart[sl2][0][j]+spart[sl2][1][j]+spart[sl2][2][j]+spart[sl2][3][j];
}

// ---------------- column pipeline on TRANSPOSED inputs (coalesced loads)
__global__ __launch_bounds__(1024) void k_colpipe(
    const float* __restrict__ avt, const float* __restrict__ et, float* __restrict__ ea)
{
    int j = blockIdx.x, t = threadIdx.x;
    __shared__ float sred[16];
    int lane = t & 63, w = t >> 6;
    float vv = avt[(size_t)j*1024 + t];
    float ss = vv*vv;
    #pragma unroll
    for(int off=1;off<64;off<<=1) ss += __shfl_xor(ss,off);
    if(lane==0) sred[w]=ss;
    __syncthreads();
    float tot = 0.f;
    #pragma unroll
    for(int i=0;i<16;i++) tot += sred[i];
    float n1 = fmaxf(sqrtf(tot), 1e-12f);
    __syncthreads();
    float o = vv/n1 + et[(size_t)j*1024 + t];
    float ss2 = o*o;
    #pragma unroll
    for(int off=1;off<64;off<<=1) ss2 += __shfl_xor(ss2,off);
    if(lane==0) sred[w]=ss2;
    __syncthreads();
    float tot2 = 0.f;
    #pragma unroll
    for(int i=0;i<16;i++) tot2 += sred[i];
    float n2 = fmaxf(sqrtf(tot2), 1e-12f);
    ea[(size_t)t*128 + j] = o/n2;
}

// ---------------- pairwise d2 (row norms from staged tiles) + global max
__global__ __launch_bounds__(256) void k_gram(
    const float* __restrict__ ea,
    float* __restrict__ d2, unsigned int* __restrict__ maxbits)
{
    int j0 = blockIdx.x*32, i0 = blockIdx.y*32, tid = threadIdx.x;
    __shared__ float sa[32*128];
    __shared__ float sb[32*128];
    __shared__ float sredm[32];
    __shared__ float sqa[32], sqb[32];
    for(int idx=tid;idx<4096;idx+=256){
        sa[idx] = ea[(size_t)i0*128 + idx];
        sb[idx] = ea[(size_t)j0*128 + idx];
    }
    __syncthreads();
    {
        int r = tid>>3, seg = tid&7;
        const float* A = sa + r*128 + seg*16;
        const float* B = sb + r*128 + seg*16;
        float pa=0.f, pb=0.f;
        #pragma unroll
        for(int i=0;i<16;i++){ pa = fmaf(A[i],A[i],pa); pb = fmaf(B[i],B[i],pb); }
        #pragma unroll
        for(int o=1;o<8;o<<=1){ pa += __shfl_xor(pa,o); pb += __shfl_xor(pb,o); }
        if(seg==0){ sqa[r]=pa; sqb[r]=pb; }
    }
    __syncthreads();
    float lm = 0.f;
    #pragma unroll
    for(int k2=0;k2<4;k2++){
        int pp = tid + k2*256;
        int li = pp>>5, lj = pp&31;
        const float4* A = (const float4*)(sa + li*128);
        const float4* B = (const float4*)(sb + lj*128);
        float acc=0.f;
        #pragma unroll 8
        for(int i=0;i<32;i++){
            float4 a=A[i], b=B[i];
            acc += a.x*b.x + a.y*b.y + a.z*b.z + a.w*b.w;
        }
        float dd = fmaxf(sqa[li] + sqb[lj] - 2.f*acc, 0.f);
        d2[(size_t)(i0+li)*1024 + j0+lj] = dd;
        lm = fmaxf(lm, dd);
    }
    lm = warp_max(lm);
    __syncthreads();
    if((tid&63)==0) sredm[tid>>6]=lm;
    __syncthreads();
    if(tid==0){
        float mm = fmaxf(fmaxf(sredm[0],sredm[1]),fmaxf(sredm[2],sredm[3]));
        atomicMax(maxbits, __float_as_uint(mm));
    }
}

// ---------------- out = 1 - sqrt(d2+eps)/maxd
__global__ __launch_bounds__(256) void k_final(
    const float* __restrict__ d2, const unsigned int* __restrict__ maxbits, float* __restrict__ out)
{
    int idx = blockIdx.x*256 + threadIdx.x;
    float md = sqrtf(__uint_as_float(*maxbits) + 1e-12f);
    out[idx] = 1.f - sqrtf(d2[idx] + 1e-12f)/md;
}

extern "C" void kernel_launch(void* const* d_in, const int* in_sizes, int n_in,
                              void* d_out, int out_size, void* d_ws, size_t ws_size,
                              hipStream_t stream)
{
    const float* x   = (const float*)d_in[0];
    const float* c1w = (const float*)d_in[1];  const float* c1b = (const float*)d_in[2];
    const float* g1g = (const float*)d_in[3];  const float* g1b = (const float*)d_in[4];
    const float* c2w = (const float*)d_in[5];  const float* c2b = (const float*)d_in[6];
    const float* g2g = (const float*)d_in[7];  const float* g2b = (const float*)d_in[8];
    const float* c3w = (const float*)d_in[9];  const float* c3b = (const float*)d_in[10];
    const float* g3g = (const float*)d_in[11]; const float* g3b = (const float*)d_in[12];
    const float* f1w = (const float*)d_in[13]; const float* f1b = (const float*)d_in[14];
    const float* wq  = (const float*)d_in[15]; const float* bq  = (const float*)d_in[16];
    const float* wk  = (const float*)d_in[17]; const float* bk  = (const float*)d_in[18];
    const float* wv  = (const float*)d_in[19]; const float* bv  = (const float*)d_in[20];

    float* W = (float*)d_ws;
    float* e0   = W;                          // 1,048,576
    float* eab  = W + 2228224;                //   131,072
    float* d2b  = W + 2359296;                // 1,048,576
    unsigned short* buf1 = (unsigned short*)(W + 4194304);  // 18,874,368 bf16
    float* wt   = W + 13631488;
    float* wqt  = W + 13762560;
    float* wkt  = W + 13778944;
    float* wvt  = W + 13795328;
    float* et   = W + 13811712;
    float* qb   = W + 13942784;
    float* kpb  = W + 14073856;
    float* vb   = W + 14204928;
    float* avt  = W + 14336000;
    unsigned int* maxb = (unsigned int*)(W + 14467072);
    short* w2bf = (short*)(W + 14467088);
    short* w3bf = (short*)(W + 14491664);
    short* w1bf = (short*)(W + 14589968);

    k_prep<<<1670,256,0,stream>>>(f1w, wq, wk, wv, c1w, c2w, c3w,
                                  wt, wqt, wkt, wvt, w1bf, w2bf, w3bf);

    k_conv1m<<<1024,1024,0,stream>>>(x, w1bf, c1b, g1g, g1b, buf1);
    k_conv23<<<1024,768,0,stream>>>(buf1, w2bf, c2b, g2g, g2b,
                                    w3bf, c3b, g3g, g3b, e0);

    k_fcqkv<<<256,512,0,stream>>>(e0, wt, f1b, et, wqt,bq, wkt,bk, wvt,bv, qb,kpb,vb);
    k_attnav<<<256,512,0,stream>>>(qb, kpb, vb, avt);

    hipMemsetAsync(maxb, 0, 4, stream);
    k_colpipe<<<128,1024,0,stream>>>(avt, et, eab);
    k_gram<<<dim3(32,32),256,0,stream>>>(eab, d2b, maxb);
    k_final<<<4096,256,0,stream>>>(d2b, maxb, (float*)d_out);
}

// Round 13
// 360.238 us; speedup vs baseline: 1.1562x; 1.1562x over previous
//
#include <hip/hip_runtime.h>
#include <hip/hip_bf16.h>
#include <math.h>

#define SELU_SCALE 1.0507009873554805f
#define SELU_SA    1.7580993408473766f   // scale*alpha

typedef __attribute__((ext_vector_type(8))) short short8;
typedef __attribute__((ext_vector_type(4))) short short4v;
typedef __attribute__((ext_vector_type(4))) float f32x4;

__device__ __forceinline__ float selu_f(float x){
    return x > 0.f ? SELU_SCALE * x : fmaf(SELU_SA, __expf(x), -SELU_SA);
}

__device__ __forceinline__ unsigned short bfc(float v){
    __hip_bfloat16 h = __float2bfloat16(v);
    return __builtin_bit_cast(unsigned short, h);
}
__device__ __forceinline__ float f_bf(unsigned short u){
    unsigned int x = ((unsigned int)u) << 16;
    return __builtin_bit_cast(float, x);
}

__device__ __forceinline__ float warp_max(float v){
    #pragma unroll
    for(int o=32;o>0;o>>=1) v = fmaxf(v,__shfl_down(v,o,64));
    return v;
}

// ---------------- unified weight prep
__global__ void k_prep(const float* __restrict__ f1w, const float* __restrict__ wq,
                       const float* __restrict__ wk, const float* __restrict__ wv,
                       const float* __restrict__ w1, const float* __restrict__ w2,
                       const float* __restrict__ w3,
                       float* __restrict__ wt, float* __restrict__ wqt,
                       float* __restrict__ wkt, float* __restrict__ wvt,
                       short* __restrict__ w1bf, short* __restrict__ w2bf,
                       short* __restrict__ w3bf){
    int idx = blockIdx.x*256 + threadIdx.x;
    if(idx < 131072){ int r = idx >> 10, cc = idx & 1023; wt[cc*128 + r] = f1w[idx]; return; }
    idx -= 131072;
    if(idx < 16384){ int r = idx >> 7, cc = idx & 127; wqt[cc*128 + r] = wq[idx]; return; }
    idx -= 16384;
    if(idx < 16384){ int r = idx >> 7, cc = idx & 127; wkt[cc*128 + r] = wk[idx]; return; }
    idx -= 16384;
    if(idx < 16384){ int r = idx >> 7, cc = idx & 127; wvt[cc*128 + r] = wv[idx]; return; }
    idx -= 16384;
    if(idx < 49152){
        int t = idx >> 11, rem = idx & 2047;
        int oc = rem >> 5, ic = rem & 31;
        w2bf[idx] = (short)bfc(w2[oc*768 + ic*24 + t]);
        return;
    }
    idx -= 49152;
    if(idx < 196608){
        int t = idx >> 13, rem = idx & 8191;
        int oc = rem >> 6, ic = rem & 63;
        w3bf[idx] = (short)bfc(w3[oc*1536 + ic*24 + t]);
        return;
    }
    idx -= 196608;
    if(idx < 1024){
        int oc = idx >> 5, k = idx & 31;
        w1bf[idx] = (k < 24) ? (short)bfc(w1[oc*24 + k]) : (short)0;
    }
}

// ============ Stage 1 (MFMA): conv1(1->32) + SELU + GN(1ch/grp) + maxpool(2,4)
__global__ __launch_bounds__(1024,1) void k_conv1m(
    const float* __restrict__ x, const short* __restrict__ w1bf,
    const float* __restrict__ bias, const float* __restrict__ g,
    const float* __restrict__ be, unsigned short* __restrict__ out)
{
    int s = blockIdx.x, tid = threadIdx.x;
    int l = tid & 63, wv = tid >> 6;          // wv 0..15
    int c = l & 15, qr = l >> 4;
    __shared__ char smem[128752];
    short* sdup = (short*)smem;               // 79 rows x 528 B = 41,712
    char* pmaxb = smem + 41712;               // [576 win x 72 B] = 41,472
    char* pminb = smem + 83184;               // 41,472
    float* sredf = (float*)(smem + 124656);   // [16][4][8][2] = 1024 floats
    __shared__ float scsh[64];                // [32 oc][sc,sh]

    const float* xs = x + (size_t)s*4608;
    for(int i = tid; i < 5056; i += 1024){
        int yp = i >> 6, xx = i & 63;
        unsigned long long pk = 0ull;
        if(yp >= 2 && yp < 74){
            const float* row = xs + (yp-2)*64;
            #pragma unroll
            for(int t=0;t<4;t++){
                int cp = xx + t;
                float f = (cp>=1 && cp<65) ? row[cp-1] : 0.f;
                pk |= (unsigned long long)bfc(f) << (16*t);
            }
        }
        *(unsigned long long*)((char*)sdup + yp*528 + (xx&3)*128 + (xx>>2)*8) = pk;
    }
    short8 a0 = *(const short8*)(w1bf + c*32 + qr*8);
    short8 a1 = *(const short8*)(w1bf + (16+c)*32 + qr*8);
    float bias8[8];
    #pragma unroll
    for(int t=0;t<2;t++)
        #pragma unroll
        for(int r=0;r<4;r++) bias8[t*4+r] = bias[t*16 + qr*4 + r];
    float ssum8[8], ssq8[8];
    #pragma unroll
    for(int i=0;i<8;i++){ ssum8[i]=0.f; ssq8[i]=0.f; }
    __syncthreads();

    int nu, py0;
    if(wv < 4){ nu = 3; py0 = wv*3; } else { nu = 2; py0 = 12 + (wv-4)*2; }
    #pragma unroll 1
    for(int u=0; u<nu; u++){
        int py = py0 + u;
        float pmx[8], pmn[8];
        #pragma unroll
        for(int i=0;i<8;i++){ pmx[i]=-INFINITY; pmn[i]=INFINITY; }
        #pragma unroll
        for(int off=0; off<4; off++){
            const char* bb = (const char*)sdup + off*128 + c*8;
            #pragma unroll
            for(int rr=0; rr<2; rr++){
                int y = py*2 + rr;
                short4v lo = *(const short4v*)(bb + (y+2*qr)*528);
                short4v hi = *(const short4v*)(bb + (y+2*qr+1)*528);
                short8 bfrag = __builtin_shufflevector(lo, hi, 0,1,2,3,4,5,6,7);
                f32x4 d0 = __builtin_amdgcn_mfma_f32_16x16x32_bf16(a0, bfrag, (f32x4){0.f,0.f,0.f,0.f}, 0,0,0);
                f32x4 d1 = __builtin_amdgcn_mfma_f32_16x16x32_bf16(a1, bfrag, (f32x4){0.f,0.f,0.f,0.f}, 0,0,0);
                #pragma unroll
                for(int r=0;r<4;r++){
                    float v0 = selu_f(d0[r] + bias8[r]);
                    float v1 = selu_f(d1[r] + bias8[4+r]);
                    ssum8[r]   += v0; ssq8[r]   = fmaf(v0,v0,ssq8[r]);
                    ssum8[4+r] += v1; ssq8[4+r] = fmaf(v1,v1,ssq8[4+r]);
                    pmx[r]   = fmaxf(pmx[r],   v0); pmn[r]   = fminf(pmn[r],   v0);
                    pmx[4+r] = fmaxf(pmx[4+r], v1); pmn[4+r] = fminf(pmn[4+r], v1);
                }
            }
        }
        int base = (py*16 + c)*72;
        #pragma unroll
        for(int t=0;t<2;t++){
            unsigned long long mpk=0ull, npk=0ull;
            #pragma unroll
            for(int r=0;r<4;r++){
                mpk |= (unsigned long long)bfc(pmx[t*4+r]) << (16*r);
                npk |= (unsigned long long)bfc(pmn[t*4+r]) << (16*r);
            }
            *(unsigned long long*)(pmaxb + base + t*32 + qr*8) = mpk;
            *(unsigned long long*)(pminb + base + t*32 + qr*8) = npk;
        }
    }
    #pragma unroll
    for(int off=1; off<16; off<<=1){
        #pragma unroll
        for(int i=0;i<8;i++){
            ssum8[i] += __shfl_xor(ssum8[i], off);
            ssq8[i]  += __shfl_xor(ssq8[i],  off);
        }
    }
    if(c == 0){
        #pragma unroll
        for(int i=0;i<8;i++){
            sredf[((wv*4 + qr)*8 + i)*2]     = ssum8[i];
            sredf[((wv*4 + qr)*8 + i)*2 + 1] = ssq8[i];
        }
    }
    __syncthreads();
    if(tid < 32){
        int oc = tid;
        int t = oc >> 4, rem = oc & 15, q = rem >> 2, r = rem & 3;
        int i = t*4 + r;
        float sum=0.f, sq=0.f;
        for(int w=0; w<16; w++){
            sum += sredf[((w*4+q)*8+i)*2];
            sq  += sredf[((w*4+q)*8+i)*2+1];
        }
        float mean = sum*(1.f/4608.f);
        float var  = sq*(1.f/4608.f) - mean*mean;
        float inv  = rsqrtf(var + 1e-5f);
        float sc = g[oc]*inv;
        scsh[oc*2]   = sc;
        scsh[oc*2+1] = be[oc] - mean*sc;
    }
    __syncthreads();
    unsigned short* ob = out + (size_t)s*18432;
    for(int i = tid; i < 18432; i += 1024){
        int oc = i / 576, wpx = i - oc*576;
        float sc = scsh[oc*2], sh = scsh[oc*2+1];
        int boff = wpx*72 + oc*2;
        float vm = f_bf(*(unsigned short*)(pmaxb + boff));
        float vn = f_bf(*(unsigned short*)(pminb + boff));
        ob[i] = bfc(fmaf(sc, (sc >= 0.f) ? vm : vn, sh));
    }
}

// ============ Fused stages 2+3 (MFMA): conv2+GN+pool -> LDS -> conv3+GN+pool -> e0
// (round-11 structure: 8 waves, phase A = ocp(2) x yq(4), phase B = 8 waves x 16 oc)
__global__ __launch_bounds__(512,2) void k_conv23(
    const unsigned short* __restrict__ in, const short* __restrict__ w2bf,
    const float* __restrict__ b2, const float* __restrict__ g2,
    const float* __restrict__ e2,
    const short* __restrict__ w3bf,
    const float* __restrict__ b3, const float* __restrict__ g3,
    const float* __restrict__ e3, float* __restrict__ e0)
{
    int s = blockIdx.x, tid = threadIdx.x;
    int l = tid & 63, wv = tid >> 6;
    int ocp = wv >> 2, yq = wv & 3;
    int xc = l & 15, qr = l >> 4;
    __shared__ char cs[69888];               // sinb 52480 (reused as pool scratch) + s3in 17408
    short* sinb = (short*)cs;
    char*  s3in = cs + 52480;
    __shared__ float sredA[2][4][2][4][2][2];
    for(int i=tid;i<17472;i+=512) ((int*)cs)[i] = 0;
    __syncthreads();
    const unsigned short* ibase = in + (size_t)s*18432;
    #pragma unroll
    for(int h=0;h<2;h++){
        int ic = (wv*2+h)*2;
        #pragma unroll
        for(int k=0;k<9;k++){
            int px = l + 64*k;
            unsigned int v0 = ibase[ic*576 + px];
            unsigned int v1 = ibase[(ic+1)*576 + px];
            int R = (px>>4)+2, C = (px&15)+1;
            int key = (C>>1)&3;
            int q0 = ic>>3;
            int byteoff = (R*20+C)*64 + (((q0^key)&3)<<4) + (ic&7)*2;
            *(unsigned int*)((char*)sinb + byteoff) = v0 | (v1<<16);
        }
    }
    __syncthreads();
    f32x4 acc[2][9];
    #pragma unroll
    for(int o=0;o<2;o++)
        #pragma unroll
        for(int yt=0;yt<9;yt++) acc[o][yt] = (f32x4){0.f,0.f,0.f,0.f};
    const short8* wb = (const short8*)w2bf;
    int arow = ocp*32 + xc;
    short8 a0 = wb[arow*4 + qr];
    short8 a1 = wb[(arow+16)*4 + qr];
    char* sb = (char*)sinb;
    for(int tap=0; tap<24; tap++){
        short8 na0, na1;
        if(tap<23){
            na0 = wb[((tap+1)*64 + arow)*4 + qr];
            na1 = wb[((tap+1)*64 + arow + 16)*4 + qr];
        }
        int kh = tap>>2, kw = tap&3;
        int C = xc + kw;
        int cb = C*64 + (((qr ^ ((C>>1)&3))&3)<<4);
        int rb = (yq*9 + kh)*1280;
        #pragma unroll
        for(int yt=0;yt<9;yt++){
            short8 bf_ = *(const short8*)(sb + rb + yt*1280 + cb);
            acc[0][yt] = __builtin_amdgcn_mfma_f32_16x16x32_bf16(a0, bf_, acc[0][yt], 0,0,0);
            acc[1][yt] = __builtin_amdgcn_mfma_f32_16x16x32_bf16(a1, bf_, acc[1][yt], 0,0,0);
        }
        a0 = na0; a1 = na1;
    }
    #pragma unroll
    for(int o=0;o<2;o++){
        int ocb = (ocp*2+o)*16 + qr*4;
        float b0 = b2[ocb], b1 = b2[ocb+1], bb2 = b2[ocb+2], b3_ = b2[ocb+3];
        float s0=0,q0s=0,s1=0,q1=0;
        #pragma unroll
        for(int yt=0;yt<9;yt++){
            float v0=selu_f(acc[o][yt][0]+b0), v1=selu_f(acc[o][yt][1]+b1);
            float v2=selu_f(acc[o][yt][2]+bb2), v3=selu_f(acc[o][yt][3]+b3_);
            acc[o][yt][0]=v0; acc[o][yt][1]=v1; acc[o][yt][2]=v2; acc[o][yt][3]=v3;
            s0+=v0+v1; q0s+=v0*v0+v1*v1; s1+=v2+v3; q1+=v2*v2+v3*v3;
        }
        #pragma unroll
        for(int off=1;off<16;off<<=1){
            s0+=__shfl_xor(s0,off); q0s+=__shfl_xor(q0s,off);
            s1+=__shfl_xor(s1,off); q1+=__shfl_xor(q1,off);
        }
        if(xc==0){
            sredA[ocp][yq][o][qr][0][0]=s0; sredA[ocp][yq][o][qr][0][1]=q0s;
            sredA[ocp][yq][o][qr][1][0]=s1; sredA[ocp][yq][o][qr][1][1]=q1;
        }
    }
    __syncthreads();
    #pragma unroll
    for(int o=0;o<2;o++){
        #pragma unroll
        for(int grp=0;grp<2;grp++){
            float ts=0, tq=0;
            #pragma unroll
            for(int y2=0;y2<4;y2++){ ts += sredA[ocp][y2][o][qr][grp][0]; tq += sredA[ocp][y2][o][qr][grp][1]; }
            float mean = ts*(1.f/1152.f);
            float var  = tq*(1.f/1152.f) - mean*mean;
            float inv  = rsqrtf(var + 1e-5f);
            int oc0 = (ocp*2+o)*16 + qr*4 + grp*2;
            float sc0 = g2[oc0]*inv,   sh0 = e2[oc0]   - mean*sc0;
            float sc1 = g2[oc0+1]*inv, sh1 = e2[oc0+1] - mean*sc1;
            #pragma unroll
            for(int yt=0;yt<9;yt++){
                acc[o][yt][grp*2]   = acc[o][yt][grp*2]*sc0 + sh0;
                acc[o][yt][grp*2+1] = acc[o][yt][grp*2+1]*sc1 + sh1;
            }
        }
        #pragma unroll
        for(int r=0;r<4;r++){
            #pragma unroll
            for(int py=0;py<3;py++){
                float m = fmaxf(fmaxf(acc[o][3*py][r],acc[o][3*py+1][r]),acc[o][3*py+2][r]);
                m = fmaxf(m, __shfl_xor(m,1));
                m = fmaxf(m, __shfl_xor(m,2));
                if((xc&3)==0){
                    int oc = (ocp*2+o)*16 + qr*4 + r;
                    int R = yq*3 + py + 2;
                    int C = (xc>>2) + 1;
                    int key = ((R&1)<<2) | (C&3);
                    int q0 = oc>>3;
                    *(unsigned short*)(s3in + (R*8+C)*128 + (((q0^key)&7)<<4) + (oc&7)*2) = bfc(m);
                }
            }
        }
    }
    __syncthreads();
    // -------- Phase B: conv3, 8 waves x 16 oc
    int yl = xc >> 2, xl = xc & 3;
    f32x4 acc3[3];
    #pragma unroll
    for(int yt=0;yt<3;yt++) acc3[yt] = (f32x4){0.f,0.f,0.f,0.f};
    const short8* wb3 = (const short8*)w3bf;
    int arow3 = wv*16 + xc;
    short8 a3 = wb3[arow3*8 + qr];
    for(int t2=0; t2<48; t2++){
        short8 na3;
        if(t2<47){
            int nt = t2+1;
            na3 = wb3[((nt>>1)*128 + arow3)*8 + (nt&1)*4 + qr];
        }
        int tap = t2>>1, ks = t2&1;
        int kh = tap>>2, kw = tap&3;
        int C = xl + kw;
        int q0 = ks*4 + qr;
        #pragma unroll
        for(int yt=0;yt<3;yt++){
            int R = yt*4 + yl + kh;
            int key = ((R&1)<<2) | (C&3);
            short8 bf_ = *(const short8*)(s3in + (R*8+C)*128 + (((q0^key)&7)<<4));
            acc3[yt] = __builtin_amdgcn_mfma_f32_16x16x32_bf16(a3, bf_, acc3[yt], 0,0,0);
        }
        a3 = na3;
    }
    // epilogue: bias + SELU + GN (group = 4 oc = this thread's qr quad)
    int ocb3 = wv*16 + qr*4;
    float c0 = b3[ocb3], c1 = b3[ocb3+1], c2 = b3[ocb3+2], c3 = b3[ocb3+3];
    float ssum=0.f, ssq=0.f;
    #pragma unroll
    for(int yt=0;yt<3;yt++){
        float v0=selu_f(acc3[yt][0]+c0), v1=selu_f(acc3[yt][1]+c1);
        float v2=selu_f(acc3[yt][2]+c2), v3=selu_f(acc3[yt][3]+c3);
        acc3[yt][0]=v0; acc3[yt][1]=v1; acc3[yt][2]=v2; acc3[yt][3]=v3;
        ssum += v0+v1+v2+v3; ssq += v0*v0+v1*v1+v2*v2+v3*v3;
    }
    #pragma unroll
    for(int off=1;off<16;off<<=1){ ssum+=__shfl_xor(ssum,off); ssq+=__shfl_xor(ssq,off); }
    float mean3 = ssum*(1.f/192.f);
    float var3  = ssq*(1.f/192.f) - mean3*mean3;
    float inv3  = rsqrtf(var3 + 1e-5f);
    float* scr = (float*)cs + wv*768;      // wave-private scratch inside dead sinb
    #pragma unroll
    for(int r=0;r<4;r++){
        int oc = ocb3 + r;
        float sc = g3[oc]*inv3, sh = e3[oc] - mean3*sc;
        #pragma unroll
        for(int yt=0;yt<3;yt++)
            scr[(qr*4+r)*48 + (yt*4+yl)*4 + xl] = acc3[yt][r]*sc + sh;
    }
    // wave-local pool 3x2: lane -> oc_l = l>>2 (16), pyw = l&3 (4), x2 in 0..1
    int oc_l = l>>2, pyw = l&3;
    const float* srd = (const float*)cs + wv*768 + oc_l*48;
    float* eo = e0 + (size_t)s*1024 + (wv*16 + oc_l)*8 + pyw*2;
    #pragma unroll
    for(int x2=0;x2<2;x2++){
        float m = srd[(pyw*3)*4 + x2*2];
        m = fmaxf(m, srd[(pyw*3)*4 + x2*2+1]);
        m = fmaxf(m, srd[(pyw*3+1)*4 + x2*2]);
        m = fmaxf(m, srd[(pyw*3+1)*4 + x2*2+1]);
        m = fmaxf(m, srd[(pyw*3+2)*4 + x2*2]);
        m = fmaxf(m, srd[(pyw*3+2)*4 + x2*2+1]);
        eo[x2] = m;
    }
}

// ---------------- FC1 + SELU + l2norm + QKV + PE, batched 4 samples/block.
__global__ __launch_bounds__(512) void k_fcqkv(
    const float* __restrict__ e0, const float* __restrict__ wt,
    const float* __restrict__ bias, float* __restrict__ et,
    const float* __restrict__ wqt, const float* __restrict__ bq,
    const float* __restrict__ wkt, const float* __restrict__ bk,
    const float* __restrict__ wvt, const float* __restrict__ bv,
    float* __restrict__ q, float* __restrict__ kp, float* __restrict__ v)
{
    int s0 = blockIdx.x*4, tid = threadIdx.x;
    int j = tid & 127, q4 = tid >> 7;
    __shared__ float se[4][1024];
    __shared__ float sp[4][4][128];
    __shared__ float sredn[4][2];
    __shared__ float se2[4][128];
    __shared__ float sp3[3][4][4][128];
    for(int i=tid;i<4096;i+=512){
        int sl = i >> 10, ii = i & 1023;
        se[sl][ii] = e0[(size_t)(s0+sl)*1024 + ii];
    }
    __syncthreads();
    float acc[4] = {0.f,0.f,0.f,0.f};
    const float* wp = wt + (size_t)q4*256*128 + j;
    const int ibase = q4*256;
    #pragma unroll 4
    for(int i=0;i<256;i++){
        float w = wp[(size_t)i*128];
        #pragma unroll
        for(int sl=0;sl<4;sl++) acc[sl] = fmaf(se[sl][ibase+i], w, acc[sl]);
    }
    #pragma unroll
    for(int sl=0;sl<4;sl++) sp[sl][q4][j] = acc[sl];
    __syncthreads();
    int sl2 = q4, lane = tid & 63, wv_ = tid >> 6;
    float vfc = selu_f(bias[j] + sp[sl2][0][j] + sp[sl2][1][j] + sp[sl2][2][j] + sp[sl2][3][j]);
    float a = vfc*vfc;
    #pragma unroll
    for(int o=1;o<64;o<<=1) a += __shfl_xor(a, o);
    if(lane==0) sredn[sl2][wv_&1] = a;
    __syncthreads();
    float den = fmaxf(sqrtf(sredn[sl2][0]+sredn[sl2][1]), 1e-12f);
    float ev = vfc/den;
    se2[sl2][j] = ev;
    et[(size_t)j*1024 + s0+sl2] = ev;
    __syncthreads();
    float aq[4]={0,0,0,0}, ak[4]={0,0,0,0}, av[4]={0,0,0,0};
    int i0b = q4*32;
    #pragma unroll 4
    for(int i=0;i<32;i++){
        float wqv = wqt[(i0b+i)*128 + j];
        float wkv = wkt[(i0b+i)*128 + j];
        float wvv = wvt[(i0b+i)*128 + j];
        #pragma unroll
        for(int sl=0;sl<4;sl++){
            float f = se2[sl][i0b+i];
            aq[sl] = fmaf(f, wqv, aq[sl]);
            ak[sl] = fmaf(f, wkv, ak[sl]);
            av[sl] = fmaf(f, wvv, av[sl]);
        }
    }
    #pragma unroll
    for(int sl=0;sl<4;sl++){
        sp3[0][sl][q4][j] = aq[sl];
        sp3[1][sl][q4][j] = ak[sl];
        sp3[2][sl][q4][j] = av[sl];
    }
    __syncthreads();
    float vq = selu_f(bq[j] + sp3[0][sl2][0][j]+sp3[0][sl2][1][j]+sp3[0][sl2][2][j]+sp3[0][sl2][3][j]);
    float vk = selu_f(bk[j] + sp3[1][sl2][0][j]+sp3[1][sl2][1][j]+sp3[1][sl2][2][j]+sp3[1][sl2][3][j]);
    float vv = selu_f(bv[j] + sp3[2][sl2][0][j]+sp3[2][sl2][1][j]+sp3[2][sl2][2][j]+sp3[2][sl2][3][j]);
    int i2 = j & ~1;
    float dv = __expf(-(float)i2 * 0.07195578412155481f);
    float ang = (float)(s0+sl2) * dv;
    float pe = (j & 1) ? cosf(ang) : sinf(ang);
    q[(size_t)(s0+sl2)*128+j]  = vq;
    kp[(size_t)(s0+sl2)*128+j] = vk + pe;
    v[(size_t)(s0+sl2)*128+j]  = vv;
}

// ---------------- fused attention, batched 4 samples/block; av written transposed
__global__ __launch_bounds__(512) void k_attnav(
    const float* __restrict__ q, const float* __restrict__ kp,
    const float* __restrict__ v, float* __restrict__ avt)
{
    int s0 = blockIdx.x*4, tid = threadIdx.x;
    __shared__ float4 sq4[4][32];
    __shared__ float p[4][1024];
    __shared__ float spart[4][4][128];
    __shared__ float smx[4][2], ssm[4][2];
    ((float*)sq4)[tid] = q[(size_t)s0*128 + tid];
    __syncthreads();
    #pragma unroll
    for(int h=0;h<2;h++){
        int t = tid + h*512;
        const float4* kr = (const float4*)(kp + (size_t)t*128);
        float d[4] = {0.f,0.f,0.f,0.f};
        #pragma unroll 4
        for(int i=0;i<32;i++){
            float4 kv = kr[i];
            #pragma unroll
            for(int sl=0;sl<4;sl++){
                float4 qv = sq4[sl][i];
                d[sl] += kv.x*qv.x + kv.y*qv.y + kv.z*qv.z + kv.w*qv.w;
            }
        }
        #pragma unroll
        for(int sl=0;sl<4;sl++) p[sl][t] = d[sl]*0.08838834764831845f;
    }
    __syncthreads();
    int sl2 = tid>>7, t2 = tid&127, lane = tid&63, wv_ = tid>>6;
    float vals[8];
    float m = -INFINITY;
    #pragma unroll
    for(int k=0;k<8;k++){ vals[k] = p[sl2][t2 + k*128]; m = fmaxf(m, vals[k]); }
    #pragma unroll
    for(int o=1;o<64;o<<=1) m = fmaxf(m, __shfl_xor(m,o));
    if(lane==0) smx[sl2][wv_&1] = m;
    __syncthreads();
    m = fmaxf(smx[sl2][0], smx[sl2][1]);
    float lsum = 0.f;
    #pragma unroll
    for(int k=0;k<8;k++){ vals[k] = __expf(vals[k]-m); lsum += vals[k]; }
    #pragma unroll
    for(int o=1;o<64;o<<=1) lsum += __shfl_xor(lsum,o);
    if(lane==0) ssm[sl2][wv_&1] = lsum;
    __syncthreads();
    float invs = 1.f/(ssm[sl2][0]+ssm[sl2][1]);
    #pragma unroll
    for(int k=0;k<8;k++) p[sl2][t2+k*128] = vals[k]*invs;
    __syncthreads();
    int j = tid & 127, q4 = tid >> 7;
    float acc[4] = {0,0,0,0};
    int t0 = q4*256;
    #pragma unroll 2
    for(int t=t0;t<t0+256;t++){
        float vv = v[(size_t)t*128 + j];
        #pragma unroll
        for(int sl=0;sl<4;sl++) acc[sl] = fmaf(p[sl][t], vv, acc[sl]);
    }
    #pragma unroll
    for(int sl=0;sl<4;sl++) spart[sl][q4][j] = acc[sl];
    __syncthreads();
    avt[(size_t)j*1024 + s0+sl2] = spart[sl2][0][j]+spart[sl2][1][j]+spart[sl2][2][j]+spart[sl2][3][j];
}

// ---------------- column pipeline on TRANSPOSED inputs (coalesced loads)
__global__ __launch_bounds__(1024) void k_colpipe(
    const float* __restrict__ avt, const float* __restrict__ et, float* __restrict__ ea)
{
    int j = blockIdx.x, t = threadIdx.x;
    __shared__ float sred[16];
    int lane = t & 63, w = t >> 6;
    float vv = avt[(size_t)j*1024 + t];
    float ss = vv*vv;
    #pragma unroll
    for(int off=1;off<64;off<<=1) ss += __shfl_xor(ss,off);
    if(lane==0) sred[w]=ss;
    __syncthreads();
    float tot = 0.f;
    #pragma unroll
    for(int i=0;i<16;i++) tot += sred[i];
    float n1 = fmaxf(sqrtf(tot), 1e-12f);
    __syncthreads();
    float o = vv/n1 + et[(size_t)j*1024 + t];
    float ss2 = o*o;
    #pragma unroll
    for(int off=1;off<64;off<<=1) ss2 += __shfl_xor(ss2,off);
    if(lane==0) sred[w]=ss2;
    __syncthreads();
    float tot2 = 0.f;
    #pragma unroll
    for(int i=0;i<16;i++) tot2 += sred[i];
    float n2 = fmaxf(sqrtf(tot2), 1e-12f);
    ea[(size_t)t*128 + j] = o/n2;
}

// ---------------- pairwise d2 (row norms from staged tiles) + global max
__global__ __launch_bounds__(256) void k_gram(
    const float* __restrict__ ea,
    float* __restrict__ d2, unsigned int* __restrict__ maxbits)
{
    int j0 = blockIdx.x*32, i0 = blockIdx.y*32, tid = threadIdx.x;
    __shared__ float sa[32*128];
    __shared__ float sb[32*128];
    __shared__ float sredm[32];
    __shared__ float sqa[32], sqb[32];
    for(int idx=tid;idx<4096;idx+=256){
        sa[idx] = ea[(size_t)i0*128 + idx];
        sb[idx] = ea[(size_t)j0*128 + idx];
    }
    __syncthreads();
    {
        int r = tid>>3, seg = tid&7;
        const float* A = sa + r*128 + seg*16;
        const float* B = sb + r*128 + seg*16;
        float pa=0.f, pb=0.f;
        #pragma unroll
        for(int i=0;i<16;i++){ pa = fmaf(A[i],A[i],pa); pb = fmaf(B[i],B[i],pb); }
        #pragma unroll
        for(int o=1;o<8;o<<=1){ pa += __shfl_xor(pa,o); pb += __shfl_xor(pb,o); }
        if(seg==0){ sqa[r]=pa; sqb[r]=pb; }
    }
    __syncthreads();
    float lm = 0.f;
    #pragma unroll
    for(int k2=0;k2<4;k2++){
        int pp = tid + k2*256;
        int li = pp>>5, lj = pp&31;
        const float4* A = (const float4*)(sa + li*128);
        const float4* B = (const float4*)(sb + lj*128);
        float acc=0.f;
        #pragma unroll 8
        for(int i=0;i<32;i++){
            float4 a=A[i], b=B[i];
            acc += a.x*b.x + a.y*b.y + a.z*b.z + a.w*b.w;
        }
        float dd = fmaxf(sqa[li] + sqb[lj] - 2.f*acc, 0.f);
        d2[(size_t)(i0+li)*1024 + j0+lj] = dd;
        lm = fmaxf(lm, dd);
    }
    lm = warp_max(lm);
    __syncthreads();
    if((tid&63)==0) sredm[tid>>6]=lm;
    __syncthreads();
    if(tid==0){
        float mm = fmaxf(fmaxf(sredm[0],sredm[1]),fmaxf(sredm[2],sredm[3]));
        atomicMax(maxbits, __float_as_uint(mm));
    }
}

// ---------------- out = 1 - sqrt(d2+eps)/maxd
__global__ __launch_bounds__(256) void k_final(
    const float* __restrict__ d2, const unsigned int* __restrict__ maxbits, float* __restrict__ out)
{
    int idx = blockIdx.x*256 + threadIdx.x;
    float md = sqrtf(__uint_as_float(*maxbits) + 1e-12f);
    out[idx] = 1.f - sqrtf(d2[idx] + 1e-12f)/md;
}

extern "C" void kernel_launch(void* const* d_in, const int* in_sizes, int n_in,
                              void* d_out, int out_size, void* d_ws, size_t ws_size,
                              hipStream_t stream)
{
    const float* x   = (const float*)d_in[0];
    const float* c1w = (const float*)d_in[1];  const float* c1b = (const float*)d_in[2];
    const float* g1g = (const float*)d_in[3];  const float* g1b = (const float*)d_in[4];
    const float* c2w = (const float*)d_in[5];  const float* c2b = (const float*)d_in[6];
    const float* g2g = (const float*)d_in[7];  const float* g2b = (const float*)d_in[8];
    const float* c3w = (const float*)d_in[9];  const float* c3b = (const float*)d_in[10];
    const float* g3g = (const float*)d_in[11]; const float* g3b = (const float*)d_in[12];
    const float* f1w = (const float*)d_in[13]; const float* f1b = (const float*)d_in[14];
    const float* wq  = (const float*)d_in[15]; const float* bq  = (const float*)d_in[16];
    const float* wk  = (const float*)d_in[17]; const float* bk  = (const float*)d_in[18];
    const float* wv  = (const float*)d_in[19]; const float* bv  = (const float*)d_in[20];

    float* W = (float*)d_ws;
    float* e0   = W;                          // 1,048,576
    float* eab  = W + 2228224;                //   131,072
    float* d2b  = W + 2359296;                // 1,048,576
    unsigned short* buf1 = (unsigned short*)(W + 4194304);  // 18,874,368 bf16
    float* wt   = W + 13631488;
    float* wqt  = W + 13762560;
    float* wkt  = W + 13778944;
    float* wvt  = W + 13795328;
    float* et   = W + 13811712;
    float* qb   = W + 13942784;
    float* kpb  = W + 14073856;
    float* vb   = W + 14204928;
    float* avt  = W + 14336000;
    unsigned int* maxb = (unsigned int*)(W + 14467072);
    short* w2bf = (short*)(W + 14467088);
    short* w3bf = (short*)(W + 14491664);
    short* w1bf = (short*)(W + 14589968);

    k_prep<<<1670,256,0,stream>>>(f1w, wq, wk, wv, c1w, c2w, c3w,
                                  wt, wqt, wkt, wvt, w1bf, w2bf, w3bf);

    k_conv1m<<<1024,1024,0,stream>>>(x, w1bf, c1b, g1g, g1b, buf1);
    k_conv23<<<1024,512,0,stream>>>(buf1, w2bf, c2b, g2g, g2b,
                                    w3bf, c3b, g3g, g3b, e0);

    k_fcqkv<<<256,512,0,stream>>>(e0, wt, f1b, et, wqt,bq, wkt,bk, wvt,bv, qb,kpb,vb);
    k_attnav<<<256,512,0,stream>>>(qb, kpb, vb, avt);

    hipMemsetAsync(maxb, 0, 4, stream);
    k_colpipe<<<128,1024,0,stream>>>(avt, et, eab);
    k_gram<<<dim3(32,32),256,0,stream>>>(eab, d2b, maxb);
    k_final<<<4096,256,0,stream>>>(d2b, maxb, (float*)d_out);
}